// Round 9
// baseline (17556.297 us; speedup 1.0000x reference)
//
#include <hip/hip_runtime.h>

#define T_ 1024
#define H_ 400
#define G4H 1600
#define NG 8            // batch groups (16 rows each)
#define RG 16           // rows per group
#define NBLK 256
#define NTHR 512
#define N0 13           // L0 blocks per group
#define N1 18           // L1 blocks per group
#define SLOT (RG * H_)  // 6400 halfs per h slot per group
#define SCOPE __HIP_MEMORY_SCOPE_AGENT

typedef float f32x4 __attribute__((ext_vector_type(4)));
typedef _Float16 h2 __attribute__((ext_vector_type(2)));
typedef _Float16 h4 __attribute__((ext_vector_type(4)));
union V4 { f32x4 f; h2 h[4]; };

// workspace layout (ints for flags, then half rings, ring depth 8)
#define F0_OFF 0                        // [NG][1024][16] ints, one word per L0 block
#define F1_OFF (NG * 1024 * 16)        // [NG][1024][32] ints, one word per L1 block
#define FD_OFF (F1_OFF + NG * 1024 * 32)  // [NG][1024][4] ints
#define FLAG_INTS (FD_OFF + NG * 1024 * 4)
#define H0_BYTE (FLAG_INTS * 4)        // 1,703,936
#define RING_B (NG * 8 * SLOT * 2)     // 819,200
#define WS_TOTAL (H0_BYTE + 2 * RING_B)

// LDS: weight slice (col-major [cols][K+pad]) + stage [16][256] halfs
#define WS0 472
#define WS1 808
#define STGB 155136
#define SMEMB (STGB + RG * 256 * 2)    // 163,328 <= 163,840

__device__ __forceinline__ float sigmf(float x) { return 1.0f / (1.0f + __expf(-x)); }

// coherent 16B load (LLC-served, bypasses non-coherent L1/L2). Valid after vwait0().
__device__ __forceinline__ void cload4(f32x4& r, const void* p) {
  asm volatile("global_load_dwordx4 %0, %1, off sc0 sc1" : "=v"(r) : "v"(p) : "memory");
}
// plain cached 16B load (immutable inputs only)
__device__ __forceinline__ void pload4(f32x4& r, const void* p) {
  asm volatile("global_load_dwordx4 %0, %1, off" : "=v"(r) : "v"(p) : "memory");
}
// drain ALL outstanding vmem (count-independent -> spill-immune)
__device__ __forceinline__ void vwait0() {
  asm volatile("s_waitcnt vmcnt(0)" ::: "memory");
  __builtin_amdgcn_sched_barrier(0);   // rule #18
}

__device__ __forceinline__ float dot2f(h2 a, h2 b, float c) {
#if __has_builtin(__builtin_amdgcn_fdot2)
  return __builtin_amdgcn_fdot2(a, b, c, false);
#else
  return fmaf((float)a[0], (float)b[0], fmaf((float)a[1], (float)b[1], c));
#endif
}

// whole-wave poll: lanes 0..n-1 each watch one per-block flag word (coalesced LLC read)
__device__ __forceinline__ void pollN(const int* base, int n) {
  const int lane = threadIdx.x & 63;
  for (;;) {
    int v = 1;
    if (lane < n)
      asm volatile("global_load_dword %0, %1, off sc0 sc1\n\ts_waitcnt vmcnt(0)"
                   : "=v"(v) : "v"(base + lane) : "memory");
    if (__all(v != 0)) return;
    __builtin_amdgcn_s_sleep(1);
  }
}
__device__ __forceinline__ void cstorei(int* p, int v) {
  asm volatile("global_store_dword %0, %1, off sc0 sc1" :: "v"(p), "v"(v) : "memory");
}
// publish: drain this block's h-stores, then single plain flag store (no RMW)
__device__ __forceinline__ void publish_flag(int* w) {
  asm volatile("s_waitcnt vmcnt(0)" ::: "memory");
  __syncthreads();
  if (threadIdx.x == 0) cstorei(w, 1);
}
__device__ __forceinline__ void cstoreh(_Float16* p, float v) {
  union { _Float16 h; unsigned short s; } cv; cv.h = (_Float16)v;
  unsigned u = cv.s;
  asm volatile("global_store_short %0, %1, off sc0 sc1" :: "v"(p), "v"(u) : "memory");
}

// one K-chunk: acc[16 rows][4 gates] += h[r][k] . w[unit cs][gate][k]
__device__ __forceinline__ void gchunk(float (&acc)[16][4], const _Float16* s_w, int ws,
                                       const _Float16* s_h, int k0, int nslot, int ks, int cs)
{
  for (int i = ks; i < nslot; i += 16) {
    V4 w0, w1, w2, w3;
    const _Float16* wb = s_w + (cs * 4) * ws + k0 + i * 8;
    w0.f = *(const f32x4*)(wb);
    w1.f = *(const f32x4*)(wb + ws);
    w2.f = *(const f32x4*)(wb + 2 * ws);
    w3.f = *(const f32x4*)(wb + 3 * ws);
    #pragma unroll
    for (int r = 0; r < 16; ++r) {
      V4 hv; hv.f = *(const f32x4*)(s_h + r * 256 + i * 8);
      #pragma unroll
      for (int q = 0; q < 4; ++q) {
        acc[r][0] = dot2f(hv.h[q], w0.h[q], acc[r][0]);
        acc[r][1] = dot2f(hv.h[q], w1.h[q], acc[r][1]);
        acc[r][2] = dot2f(hv.h[q], w2.h[q], acc[r][2]);
        acc[r][3] = dot2f(hv.h[q], w3.h[q], acc[r][3]);
      }
    }
  }
}

// ---------------- Layer 0: 16 rows, ~31 units. K = 464: h0(400)|x(56)|pad(8). 1 LLC exposure ----------------
__device__ void run_l0(int jj, int grp,
    const float* __restrict__ xr, const float* __restrict__ xc,
    const float* __restrict__ Wx0, const float* __restrict__ Wh0, const float* __restrict__ b0,
    _Float16* __restrict__ h0g, int* F0, int* F1, unsigned char* smem)
{
  const int tid = threadIdx.x;
  _Float16* s_w = (_Float16*)smem;
  _Float16* s_h = (_Float16*)(smem + STGB);
  const int u0 = jj * H_ / N0, u1 = (jj + 1) * H_ / N0;

  for (int idx = tid; idx < 128 * WS0; idx += NTHR) {
    int col = idx / WS0, k = idx - col * WS0;
    int u = col >> 2, g = col & 3, uu = u0 + u;
    float v = 0.f;
    if (uu < u1 && k < 456)
      v = (k < 400) ? Wh0[k * G4H + g * H_ + uu] : Wx0[(k - 400) * G4H + g * H_ + uu];
    s_w[idx] = (_Float16)v;
  }
  __syncthreads();

  const int cs = tid >> 4, ks = tid & 15;
  const int uu = u0 + cs;
  const bool act = (uu < u1);
  float bi0 = 0.f, bi1 = 0.f, bi2 = 0.f, bi3 = 0.f;
  if (act) { bi0 = b0[uu]; bi1 = b0[H_ + uu]; bi2 = b0[2 * H_ + uu]; bi3 = b0[3 * H_ + uu]; }
  float cst = 0.f;
  const int wv = tid >> 6;

  f32x4 rx, rA, rB;
  for (int s = 0; s < T_; ++s) {
    const _Float16* h0p = h0g + ((s - 1) & 7) * SLOT;
    _Float16* h0n = h0g + (s & 7) * SLOT;

    if (tid < 224) {          // x pre-issue (plain cached)
      int row = tid / 14, c4 = tid - row * 14, kf = c4 * 4;
      int rg = grp * RG + row;
      const float* p = (kf < 40) ? xr + (rg * T_ + s) * 40 + kf
                                 : xc + (rg * T_ + s) * 16 + (kf - 40);
      pload4(rx, p);
    }
    if (wv == 0 && s >= 1) pollN(F0 + (s - 1) * 16, N0);   // h0(s-1) complete
    if (wv == 1 && s >= 8) pollN(F1 + (s - 8) * 32, N1);   // slot s&7 free
    __syncthreads();

    // issue ALL h loads, one wait
    { int row = tid >> 5, sl = tid & 31; cload4(rA, h0p + row * H_ + sl * 8); }
    if (tid < 288) { int row = tid / 18, sl = tid - row * 18;
      cload4(rB, h0p + row * H_ + 256 + sl * 8); }
    vwait0();   // single LLC exposure (drains rx too)

    float acc[16][4];
    #pragma unroll
    for (int r = 0; r < 16; ++r)
      #pragma unroll
      for (int g = 0; g < 4; ++g) acc[r][g] = 0.f;

    { int row = tid >> 5, sl = tid & 31; *(f32x4*)(s_h + row * 256 + sl * 8) = rA; }
    __syncthreads();
    gchunk(acc, s_w, WS0, s_h, 0, 32, ks, cs);
    __syncthreads();
    if (tid < 288) { int row = tid / 18, sl = tid - row * 18;
      *(f32x4*)(s_h + row * 256 + sl * 8) = rB; }
    if (tid < 224) { int row = tid / 14, c4 = tid - row * 14;
      h4 hv; hv[0] = (_Float16)rx[0]; hv[1] = (_Float16)rx[1];
             hv[2] = (_Float16)rx[2]; hv[3] = (_Float16)rx[3];
      *(h4*)(s_h + row * 256 + 144 + c4 * 4) = hv; }
    __syncthreads();
    gchunk(acc, s_w, WS0, s_h, 256, 26, ks, cs);   // pad cols 200-207: stale-finite, zero weights

    #pragma unroll
    for (int r = 0; r < 16; ++r)
      #pragma unroll
      for (int g = 0; g < 4; ++g) {
        float v = acc[r][g];
        v += __shfl_xor(v, 1); v += __shfl_xor(v, 2);
        v += __shfl_xor(v, 4); v += __shfl_xor(v, 8);
        acc[r][g] = v;
      }
    float g0 = 0.f, g1 = 0.f, g2 = 0.f, g3 = 0.f;
    #pragma unroll
    for (int r = 0; r < 16; ++r)
      if (ks == r) { g0 = acc[r][0]; g1 = acc[r][1]; g2 = acc[r][2]; g3 = acc[r][3]; }
    float iv = sigmf(g0 + bi0), fv = sigmf(g1 + bi1);
    float gv = tanhf(g2 + bi2), ov = sigmf(g3 + bi3);
    cst = fv * cst + iv * gv;
    float hval = ov * tanhf(cst);
    if (act) cstoreh(h0n + ks * H_ + uu, hval);
    publish_flag(F0 + s * 16 + jj);
  }
}

// ---------------- Layer 1: 16 rows, ~23 units. K = 800: h0(s)|h1(s-1). 1 LLC exposure ----------------
__device__ void run_l1(int jj, int grp,
    const float* __restrict__ Wx1, const float* __restrict__ Wh1, const float* __restrict__ b1,
    const _Float16* __restrict__ h0g, _Float16* __restrict__ h1g,
    int* F0, int* F1, int* FD, unsigned char* smem)
{
  const int tid = threadIdx.x;
  _Float16* s_w = (_Float16*)smem;
  _Float16* s_h = (_Float16*)(smem + STGB);
  const int u0 = jj * H_ / N1, u1 = (jj + 1) * H_ / N1;

  for (int idx = tid; idx < 96 * WS1; idx += NTHR) {
    int col = idx / WS1, k = idx - col * WS1;
    int u = col >> 2, g = col & 3, uu = u0 + u;
    float v = 0.f;
    if (uu < u1 && k < 800)
      v = (k < 400) ? Wx1[k * G4H + g * H_ + uu] : Wh1[(k - 400) * G4H + g * H_ + uu];
    s_w[idx] = (_Float16)v;
  }
  __syncthreads();

  const bool thr = tid < 384;
  const int cs = tid >> 4, ks = tid & 15;
  const int uu = u0 + cs;
  const bool act = thr && (uu < u1);
  float bi0 = 0.f, bi1 = 0.f, bi2 = 0.f, bi3 = 0.f;
  if (act) { bi0 = b1[uu]; bi1 = b1[H_ + uu]; bi2 = b1[2 * H_ + uu]; bi3 = b1[3 * H_ + uu]; }
  float cst = 0.f;
  const int wv = tid >> 6;

  // per-thread constant slot mapping: slot = row*100 + c, K index = c*8
  int ro[4], cc[4];
  #pragma unroll
  for (int k = 0; k < 4; ++k) {
    int sl = tid + 512 * k;
    ro[k] = sl / 100; cc[k] = sl - ro[k] * 100;
  }

  f32x4 r0, r1, r2, r3;
  for (int s = 0; s < T_; ++s) {
    const _Float16* h0c = h0g + (s & 7) * SLOT;
    const _Float16* h1p = h1g + ((s - 1) & 7) * SLOT;
    _Float16* h1n = h1g + (s & 7) * SLOT;

    if (wv == 0)           pollN(F0 + s * 16, N0);           // h0(s)
    if (wv == 1 && s >= 1) pollN(F1 + (s - 1) * 32, N1);     // h1(s-1)
    if (wv == 2 && s >= 8) pollN(FD + (s - 8) * 4, 1);       // dense freed slot
    __syncthreads();

    // issue ALL 1600 slots (3-4 cloads/thread), one wait
    auto src = [&](int k) -> const _Float16* {
      int kh = cc[k] * 8;
      return (kh < 400) ? h0c + ro[k] * H_ + kh : h1p + ro[k] * H_ + (kh - 400);
    };
    cload4(r0, src(0)); cload4(r1, src(1)); cload4(r2, src(2));
    if (tid < 64) cload4(r3, src(3));
    vwait0();   // single LLC exposure

    float acc[16][4];
    #pragma unroll
    for (int r = 0; r < 16; ++r)
      #pragma unroll
      for (int g = 0; g < 4; ++g) acc[r][g] = 0.f;

    #pragma unroll
    for (int p = 0; p < 4; ++p) {
      if (p > 0) __syncthreads();
      const int lo = 32 * p, hi = 32 * p + 32;
      if (cc[0] >= lo && cc[0] < hi) *(f32x4*)(s_h + ro[0] * 256 + (cc[0] - lo) * 8) = r0;
      if (cc[1] >= lo && cc[1] < hi) *(f32x4*)(s_h + ro[1] * 256 + (cc[1] - lo) * 8) = r1;
      if (cc[2] >= lo && cc[2] < hi) *(f32x4*)(s_h + ro[2] * 256 + (cc[2] - lo) * 8) = r2;
      if (tid < 64 && cc[3] >= lo && cc[3] < hi) *(f32x4*)(s_h + ro[3] * 256 + (cc[3] - lo) * 8) = r3;
      __syncthreads();
      if (thr) gchunk(acc, s_w, WS1, s_h, 256 * p, (p < 3) ? 32 : 4, ks, cs);
    }

    if (thr) {
      #pragma unroll
      for (int r = 0; r < 16; ++r)
        #pragma unroll
        for (int g = 0; g < 4; ++g) {
          float v = acc[r][g];
          v += __shfl_xor(v, 1); v += __shfl_xor(v, 2);
          v += __shfl_xor(v, 4); v += __shfl_xor(v, 8);
          acc[r][g] = v;
        }
      float g0 = 0.f, g1 = 0.f, g2 = 0.f, g3 = 0.f;
      #pragma unroll
      for (int r = 0; r < 16; ++r)
        if (ks == r) { g0 = acc[r][0]; g1 = acc[r][1]; g2 = acc[r][2]; g3 = acc[r][3]; }
      float iv = sigmf(g0 + bi0), fv = sigmf(g1 + bi1);
      float gv = tanhf(g2 + bi2), ov = sigmf(g3 + bi3);
      cst = fv * cst + iv * gv;
      float hval = ov * tanhf(cst);
      if (act) cstoreh(h1n + ks * H_ + uu, hval);
    }
    publish_flag(F1 + s * 32 + jj);
  }
}

// ---------------- Dense: out(s) = h1(s) @ Wd + bd, 16 rows ----------------
__device__ void run_dense(int grp, const float* __restrict__ Wd, const float* __restrict__ bd,
                          const _Float16* __restrict__ h1g, float* __restrict__ out,
                          int* F1, int* FD, unsigned char* smem)
{
  const int tid = threadIdx.x;
  _Float16* s_wd = (_Float16*)smem;   // [4][404]
  for (int idx = tid; idx < 1600; idx += NTHR) {
    int k = idx >> 2, f = idx & 3;
    s_wd[f * 404 + k] = (_Float16)Wd[idx];
  }
  __syncthreads();
  const bool thr = tid < 256;
  const int row = tid >> 4, ks = tid & 15;
  const int rg = grp * RG + row;
  const float bdv = (ks < 4) ? bd[ks] : 0.f;
  const int wv = tid >> 6;
  f32x4 r0, r1, r2, r3;
  for (int s = 0; s < T_; ++s) {
    if (wv == 0) pollN(F1 + s * 32, N1);
    __syncthreads();
    const _Float16* hrow = h1g + (s & 7) * SLOT + row * H_;
    if (thr) {
      cload4(r0, hrow + ks * 8);
      cload4(r1, hrow + (ks + 16) * 8);
      cload4(r2, hrow + (ks + 32) * 8);
      if (ks < 2) cload4(r3, hrow + (48 + ks) * 8);
    }
    vwait0();
    __syncthreads();                       // all reads of slot s&7 retired
    if (tid == 0) cstorei(FD + s * 4, 1);  // release slot
    if (thr) {
      float a0 = 0.f, a1 = 0.f, a2 = 0.f, a3 = 0.f;
      auto dproc = [&](const f32x4& rv, int sl) {
        V4 hv; hv.f = rv;
        #pragma unroll
        for (int q = 0; q < 4; ++q) {
          int k = sl * 8 + q * 2;
          h2 hp = hv.h[q];
          a0 = dot2f(hp, *(const h2*)(s_wd + k), a0);
          a1 = dot2f(hp, *(const h2*)(s_wd + 404 + k), a1);
          a2 = dot2f(hp, *(const h2*)(s_wd + 808 + k), a2);
          a3 = dot2f(hp, *(const h2*)(s_wd + 1212 + k), a3);
        }
      };
      dproc(r0, ks); dproc(r1, ks + 16); dproc(r2, ks + 32);
      if (ks < 2) dproc(r3, 48 + ks);
      a0 += __shfl_xor(a0, 1); a0 += __shfl_xor(a0, 2); a0 += __shfl_xor(a0, 4); a0 += __shfl_xor(a0, 8);
      a1 += __shfl_xor(a1, 1); a1 += __shfl_xor(a1, 2); a1 += __shfl_xor(a1, 4); a1 += __shfl_xor(a1, 8);
      a2 += __shfl_xor(a2, 1); a2 += __shfl_xor(a2, 2); a2 += __shfl_xor(a2, 4); a2 += __shfl_xor(a2, 8);
      a3 += __shfl_xor(a3, 1); a3 += __shfl_xor(a3, 2); a3 += __shfl_xor(a3, 4); a3 += __shfl_xor(a3, 8);
      float o = a0;
      if (ks == 1) o = a1;
      if (ks == 2) o = a2;
      if (ks == 3) o = a3;
      if (ks < 4) out[(rg * T_ + s) * 4 + ks] = o + bdv;
    }
  }
}

__global__ __launch_bounds__(NTHR, 1) void rnn_kernel(
    const float* __restrict__ xr, const float* __restrict__ xc,
    const float* __restrict__ Wx0, const float* __restrict__ Wh0, const float* __restrict__ b0,
    const float* __restrict__ Wx1, const float* __restrict__ Wh1, const float* __restrict__ b1,
    const float* __restrict__ Wd, const float* __restrict__ bd,
    float* __restrict__ out, float* ws)
{
  __shared__ __align__(16) unsigned char smem[SMEMB];
  const int bid = blockIdx.x;
  const int grp = bid >> 5, j = bid & 31;
  int* flags = (int*)ws;
  int* F0 = flags + F0_OFF + grp * 1024 * 16;
  int* F1 = flags + F1_OFF + grp * 1024 * 32;
  int* FD = flags + FD_OFF + grp * 1024 * 4;
  _Float16* h0g = (_Float16*)((char*)ws + H0_BYTE) + grp * 8 * SLOT;
  _Float16* h1g = (_Float16*)((char*)ws + H0_BYTE + RING_B) + grp * 8 * SLOT;
  if (j < N0)            run_l0(j, grp, xr, xc, Wx0, Wh0, b0, h0g, F0, F1, smem);
  else if (j < N0 + N1)  run_l1(j - N0, grp, Wx1, Wh1, b1, h0g, h1g, F0, F1, FD, smem);
  else                   run_dense(grp, Wd, bd, h1g, out, F1, FD, smem);
}

extern "C" void kernel_launch(void* const* d_in, const int* in_sizes, int n_in,
                              void* d_out, int out_size, void* d_ws, size_t ws_size,
                              hipStream_t stream) {
  const float* xr  = (const float*)d_in[0];
  const float* xc  = (const float*)d_in[1];
  const float* Wx0 = (const float*)d_in[2];
  const float* Wh0 = (const float*)d_in[3];
  const float* b0  = (const float*)d_in[4];
  const float* Wx1 = (const float*)d_in[5];
  const float* Wh1 = (const float*)d_in[6];
  const float* b1  = (const float*)d_in[7];
  const float* Wd  = (const float*)d_in[8];
  const float* bd  = (const float*)d_in[9];
  float* out = (float*)d_out;
  float* ws  = (float*)d_ws;

  // zero flags + both h rings (re-zeroed every launch -> deterministic replays)
  hipMemsetAsync(d_ws, 0, WS_TOTAL, stream);
  hipLaunchKernelGGL(rnn_kernel, dim3(NBLK), dim3(NTHR), 0, stream,
                     xr, xc, Wx0, Wh0, b0, Wx1, Wh1, b1, Wd, bd, out, ws);
}

// Round 10
// 14680.594 us; speedup vs baseline: 1.1959x; 1.1959x over previous
//
#include <hip/hip_runtime.h>

#define T_ 1024
#define H_ 400
#define G4H 1600
#define NG 8            // batch groups (16 rows each)
#define RG 16           // rows per group
#define NBLK 256
#define NTHR 512
#define N0 14           // L0 blocks per group
#define N1 17           // L1 blocks per group
#define SLOT (RG * H_)  // 6400 halfs per h slot per group
#define SCOPE __HIP_MEMORY_SCOPE_AGENT

typedef float f32x4 __attribute__((ext_vector_type(4)));
typedef _Float16 h2 __attribute__((ext_vector_type(2)));
typedef _Float16 h4 __attribute__((ext_vector_type(4)));
union V4 { f32x4 f; h2 h[4]; };

// LDS: weight slice (col-major [cols][K+pad]) + stage [16][256] halfs
#define WS0 472                     // L0 K-stride (464 used)
#define WS1 808                     // L1 K-stride (800 used)
#define STGB 155136                 // stage offset = L1 weight bytes (96*808*2)
#define SMEMB (STGB + RG*256*2)     // 163328 <= 163840

__device__ __forceinline__ float sigmf(float x) { return 1.0f / (1.0f + __expf(-x)); }

// coherent 16B load (LLC-served, bypasses non-coherent L1/L2). Valid after vwait0().
__device__ __forceinline__ void cload4(f32x4& r, const void* p) {
  asm volatile("global_load_dwordx4 %0, %1, off sc0 sc1" : "=v"(r) : "v"(p) : "memory");
}
// plain cached 16B load (immutable inputs only)
__device__ __forceinline__ void pload4(f32x4& r, const void* p) {
  asm volatile("global_load_dwordx4 %0, %1, off" : "=v"(r) : "v"(p) : "memory");
}
// drain ALL outstanding vmem (count-independent -> spill-immune)
__device__ __forceinline__ void vwait0() {
  asm volatile("s_waitcnt vmcnt(0)" ::: "memory");
  __builtin_amdgcn_sched_barrier(0);   // rule #18
}

__device__ __forceinline__ float dot2f(h2 a, h2 b, float c) {
#if __has_builtin(__builtin_amdgcn_fdot2)
  return __builtin_amdgcn_fdot2(a, b, c, false);
#else
  return fmaf((float)a[0], (float)b[0], fmaf((float)a[1], (float)b[1], c));
#endif
}

__device__ __forceinline__ void waitflag(const int* f, int tgt) {
  while (__hip_atomic_load(f, __ATOMIC_RELAXED, SCOPE) < tgt)
    __builtin_amdgcn_s_sleep(1);
}
__device__ __forceinline__ void publish(int* f) {
  asm volatile("s_waitcnt vmcnt(0)" ::: "memory");   // drain this thread's h-stores
  __syncthreads();                                    // all threads drained
  if (threadIdx.x == 0) __hip_atomic_fetch_add(f, 1, __ATOMIC_RELAXED, SCOPE);
}
__device__ __forceinline__ void cstoreh(_Float16* p, float v) {
  union { _Float16 h; unsigned short s; } cv; cv.h = (_Float16)v;
  unsigned u = cv.s;
  asm volatile("global_store_short %0, %1, off sc0 sc1" :: "v"(p), "v"(u) : "memory");
}

// one K-chunk: acc[16 rows][4 gates] += h[r][i*8..] . w[unit cs][gate][k0w + i*8..]
__device__ __forceinline__ void gchunk(float (&acc)[16][4], const _Float16* s_w, int ws,
                                       const _Float16* s_h, int k0w, int nslot, int ks, int cs)
{
  for (int i = ks; i < nslot; i += 16) {
    V4 w0, w1, w2, w3;
    const _Float16* wb = s_w + (cs * 4) * ws + k0w + i * 8;
    w0.f = *(const f32x4*)(wb);
    w1.f = *(const f32x4*)(wb + ws);
    w2.f = *(const f32x4*)(wb + 2 * ws);
    w3.f = *(const f32x4*)(wb + 3 * ws);
    #pragma unroll
    for (int r = 0; r < 16; ++r) {
      V4 hv; hv.f = *(const f32x4*)(s_h + r * 256 + i * 8);
      #pragma unroll
      for (int q = 0; q < 4; ++q) {
        acc[r][0] = dot2f(hv.h[q], w0.h[q], acc[r][0]);
        acc[r][1] = dot2f(hv.h[q], w1.h[q], acc[r][1]);
        acc[r][2] = dot2f(hv.h[q], w2.h[q], acc[r][2]);
        acc[r][3] = dot2f(hv.h[q], w3.h[q], acc[r][3]);
      }
    }
  }
}

// ---------------- Layer 0: 16 rows, ~29 units. K = 464: h0(400)|x(56)|pad(8) ----------------
__device__ void run_l0(int jj, int grp,
    const float* __restrict__ xr, const float* __restrict__ xc,
    const float* __restrict__ Wx0, const float* __restrict__ Wh0, const float* __restrict__ b0,
    _Float16* __restrict__ h0g, int* f0, int* f1, unsigned char* smem)
{
  const int tid = threadIdx.x;
  _Float16* s_w = (_Float16*)smem;
  _Float16* s_h = (_Float16*)(smem + STGB);
  const int u0 = jj * H_ / N0, u1 = (jj + 1) * H_ / N0;

  for (int idx = tid; idx < 128 * WS0; idx += NTHR) {
    int col = idx / WS0, k = idx - col * WS0;
    int u = col >> 2, g = col & 3, uu = u0 + u;
    float v = 0.f;
    if (uu < u1 && k < 456)
      v = (k < 400) ? Wh0[k * G4H + g * H_ + uu] : Wx0[(k - 400) * G4H + g * H_ + uu];
    s_w[idx] = (_Float16)v;
  }
  __syncthreads();

  const int cs = tid >> 4, ks = tid & 15;
  const int uu = u0 + cs;
  const bool act = (uu < u1);
  float bi0 = 0.f, bi1 = 0.f, bi2 = 0.f, bi3 = 0.f;
  if (act) { bi0 = b0[uu]; bi1 = b0[H_ + uu]; bi2 = b0[2 * H_ + uu]; bi3 = b0[3 * H_ + uu]; }
  float cst = 0.f;   // cell state of (row ks, unit uu)

  f32x4 rx, rA, rB;
  for (int s = 0; s < T_; ++s) {
    const _Float16* h0p = h0g + ((s - 1) & 3) * SLOT;
    _Float16* h0n = h0g + (s & 3) * SLOT;

    // x pre-issue (plain cached): 16 rows x 14 x4-slots = 224 loads
    if (tid < 224) {
      int row = tid / 14, c4 = tid - row * 14, kf = c4 * 4;
      int rg = grp * RG + row;
      const float* p = (kf < 40) ? xr + (rg * T_ + s) * 40 + kf
                                 : xc + (rg * T_ + s) * 16 + (kf - 40);
      pload4(rx, p);
    }
    if (tid == 0 && s >= 1)  waitflag(f0 + s - 1, N0);   // h0(s-1) complete
    if (tid == 64 && s >= 4) waitflag(f1 + s - 4, N1);   // slot s&3 free
    __syncthreads();

    // chunk 0: K[0,256): 1 cload/thread; prefetch chunk-1 h after its wait
    { int row = tid >> 5, sl = tid & 31;
      cload4(rA, h0p + row * H_ + sl * 8); }
    vwait0();                                   // drains rx + c0
    { int row = tid >> 5, sl = tid & 31;
      *(f32x4*)(s_h + row * 256 + sl * 8) = rA; }
    if (tid < 288) {                            // c1 h-part: K[256,400): 18 slots/row
      int row = tid / 18, sl = tid - row * 18;
      cload4(rB, h0p + row * H_ + 256 + sl * 8);
    }
    __syncthreads();

    float acc[16][4];
    #pragma unroll
    for (int r = 0; r < 16; ++r)
      #pragma unroll
      for (int g = 0; g < 4; ++g) acc[r][g] = 0.f;

    gchunk(acc, s_w, WS0, s_h, 0, 32, ks, cs);
    __syncthreads();
    vwait0();
    if (tid < 288) { int row = tid / 18, sl = tid - row * 18;
      *(f32x4*)(s_h + row * 256 + sl * 8) = rB; }
    if (tid < 224) { int row = tid / 14, c4 = tid - row * 14;
      h4 hv; hv[0] = (_Float16)rx[0]; hv[1] = (_Float16)rx[1];
             hv[2] = (_Float16)rx[2]; hv[3] = (_Float16)rx[3];
      *(h4*)(s_h + row * 256 + 144 + c4 * 4) = hv; }   // x -> cols 144-199
    __syncthreads();
    // cols 200-207 keep chunk-0 h values (finite; zero weights at K 456-463)
    gchunk(acc, s_w, WS0, s_h, 256, 26, ks, cs);

    #pragma unroll
    for (int r = 0; r < 16; ++r)
      #pragma unroll
      for (int g = 0; g < 4; ++g) {
        float v = acc[r][g];
        v += __shfl_xor(v, 1); v += __shfl_xor(v, 2);
        v += __shfl_xor(v, 4); v += __shfl_xor(v, 8);
        acc[r][g] = v;
      }
    float g0 = 0.f, g1 = 0.f, g2 = 0.f, g3 = 0.f;
    #pragma unroll
    for (int r = 0; r < 16; ++r)
      if (ks == r) { g0 = acc[r][0]; g1 = acc[r][1]; g2 = acc[r][2]; g3 = acc[r][3]; }
    float iv = sigmf(g0 + bi0), fv = sigmf(g1 + bi1);
    float gv = tanhf(g2 + bi2), ov = sigmf(g3 + bi3);
    cst = fv * cst + iv * gv;
    float hval = ov * tanhf(cst);
    if (act) cstoreh(h0n + ks * H_ + uu, hval);
    publish(f0 + s);
  }
}

// ---------------- Layer 1: 16 rows, ~24 units. K = 800 split: h0-half first, h1-half late ----------------
__device__ void run_l1(int jj, int grp,
    const float* __restrict__ Wx1, const float* __restrict__ Wh1, const float* __restrict__ b1,
    const _Float16* __restrict__ h0g, _Float16* __restrict__ h1g,
    int* f0, int* f1, int* fD, unsigned char* smem)
{
  const int tid = threadIdx.x;
  _Float16* s_w = (_Float16*)smem;
  _Float16* s_h = (_Float16*)(smem + STGB);
  const int u0 = jj * H_ / N1, u1 = (jj + 1) * H_ / N1;

  for (int idx = tid; idx < 96 * WS1; idx += NTHR) {
    int col = idx / WS1, k = idx - col * WS1;
    int u = col >> 2, g = col & 3, uu = u0 + u;
    float v = 0.f;
    if (uu < u1 && k < 800)
      v = (k < 400) ? Wx1[k * G4H + g * H_ + uu] : Wh1[(k - 400) * G4H + g * H_ + uu];
    s_w[idx] = (_Float16)v;
  }
  __syncthreads();

  const bool thr = tid < 384;                 // 24 cs-groups x 16 ks
  const int cs = tid >> 4, ks = tid & 15;
  const int uu = u0 + cs;
  const bool act = thr && (uu < u1);
  float bi0 = 0.f, bi1 = 0.f, bi2 = 0.f, bi3 = 0.f;
  if (act) { bi0 = b1[uu]; bi1 = b1[H_ + uu]; bi2 = b1[2 * H_ + uu]; bi3 = b1[3 * H_ + uu]; }
  float cst = 0.f;

  f32x4 rA, rB;
  for (int s = 0; s < T_; ++s) {
    const _Float16* h0c = h0g + (s & 3) * SLOT;          // h0(s)
    const _Float16* h1p = h1g + ((s - 1) & 3) * SLOT;    // h1(s-1)
    _Float16* h1n = h1g + (s & 3) * SLOT;

    // ---- phase A: h0(s) half (pre-published thanks to L0's lead) ----
    if (tid == 0)            waitflag(f0 + s, N0);       // h0(s) ready
    if (tid == 64 && s >= 4) waitflag(fD + s - 4, 1);    // dense freed slot s&3
    __syncthreads();

    float acc[16][4];
    #pragma unroll
    for (int r = 0; r < 16; ++r)
      #pragma unroll
      for (int g = 0; g < 4; ++g) acc[r][g] = 0.f;

    { int row = tid >> 5, sl = tid & 31;                 // h0[0,256)
      cload4(rA, h0c + row * H_ + sl * 8); }
    if (tid < 288) { int row = tid / 18, sl = tid - row * 18;   // h0[256,400)
      cload4(rB, h0c + row * H_ + 256 + sl * 8); }
    vwait0();
    { int row = tid >> 5, sl = tid & 31;
      *(f32x4*)(s_h + row * 256 + sl * 8) = rA; }
    __syncthreads();
    if (thr) gchunk(acc, s_w, WS1, s_h, 0, 32, ks, cs);
    __syncthreads();
    if (tid < 288) { int row = tid / 18, sl = tid - row * 18;
      *(f32x4*)(s_h + row * 256 + sl * 8) = rB; }
    __syncthreads();
    if (thr) gchunk(acc, s_w, WS1, s_h, 256, 18, ks, cs);

    // ---- phase B: h1(s-1) half (poll AFTER phase A hid the jitter) ----
    if (tid == 0 && s >= 1) waitflag(f1 + s - 1, N1);    // h1(s-1) ready
    __syncthreads();
    { int row = tid >> 5, sl = tid & 31;                 // h1[0,256) -> K 400..656
      cload4(rA, h1p + row * H_ + sl * 8); }
    if (tid < 288) { int row = tid / 18, sl = tid - row * 18;   // h1[256,400) -> K 656..800
      cload4(rB, h1p + row * H_ + 256 + sl * 8); }
    vwait0();
    { int row = tid >> 5, sl = tid & 31;
      *(f32x4*)(s_h + row * 256 + sl * 8) = rA; }
    __syncthreads();
    if (thr) gchunk(acc, s_w, WS1, s_h, 400, 32, ks, cs);
    __syncthreads();
    if (tid < 288) { int row = tid / 18, sl = tid - row * 18;
      *(f32x4*)(s_h + row * 256 + sl * 8) = rB; }
    __syncthreads();
    if (thr) gchunk(acc, s_w, WS1, s_h, 656, 18, ks, cs);

    if (thr) {
      #pragma unroll
      for (int r = 0; r < 16; ++r)
        #pragma unroll
        for (int g = 0; g < 4; ++g) {
          float v = acc[r][g];
          v += __shfl_xor(v, 1); v += __shfl_xor(v, 2);
          v += __shfl_xor(v, 4); v += __shfl_xor(v, 8);
          acc[r][g] = v;
        }
      float g0 = 0.f, g1 = 0.f, g2 = 0.f, g3 = 0.f;
      #pragma unroll
      for (int r = 0; r < 16; ++r)
        if (ks == r) { g0 = acc[r][0]; g1 = acc[r][1]; g2 = acc[r][2]; g3 = acc[r][3]; }
      float iv = sigmf(g0 + bi0), fv = sigmf(g1 + bi1);
      float gv = tanhf(g2 + bi2), ov = sigmf(g3 + bi3);
      cst = fv * cst + iv * gv;
      float hval = ov * tanhf(cst);
      if (act) cstoreh(h1n + ks * H_ + uu, hval);
    }
    publish(f1 + s);
  }
}

// ---------------- Dense: out(s) = h1(s) @ Wd + bd, 16 rows ----------------
__device__ void run_dense(int grp, const float* __restrict__ Wd, const float* __restrict__ bd,
                          const _Float16* __restrict__ h1g, float* __restrict__ out,
                          int* f1, int* fD, unsigned char* smem)
{
  const int tid = threadIdx.x;
  _Float16* s_wd = (_Float16*)smem;   // [4][404]
  for (int idx = tid; idx < 1600; idx += NTHR) {
    int k = idx >> 2, f = idx & 3;
    s_wd[f * 404 + k] = (_Float16)Wd[idx];
  }
  __syncthreads();
  const bool thr = tid < 256;
  const int row = tid >> 4, ks = tid & 15;
  const int rg = grp * RG + row;
  const float bdv = (ks < 4) ? bd[ks] : 0.f;
  f32x4 r0, r1, r2, r3;
  for (int s = 0; s < T_; ++s) {
    if (tid == 0) waitflag(f1 + s, N1);
    __syncthreads();
    const _Float16* hrow = h1g + (s & 3) * SLOT + row * H_;
    if (thr) {
      cload4(r0, hrow + ks * 8);
      cload4(r1, hrow + (ks + 16) * 8);
      cload4(r2, hrow + (ks + 32) * 8);
      if (ks < 2) cload4(r3, hrow + (48 + ks) * 8);
    }
    vwait0();
    __syncthreads();                   // all reads of slot s&3 retired
    if (tid == 0) __hip_atomic_fetch_add(fD + s, 1, __ATOMIC_RELAXED, SCOPE);
    if (thr) {
      float a0 = 0.f, a1 = 0.f, a2 = 0.f, a3 = 0.f;
      auto dproc = [&](const f32x4& rv, int sl) {
        V4 hv; hv.f = rv;
        #pragma unroll
        for (int q = 0; q < 4; ++q) {
          int k = sl * 8 + q * 2;
          h2 hp = hv.h[q];
          a0 = dot2f(hp, *(const h2*)(s_wd + k), a0);
          a1 = dot2f(hp, *(const h2*)(s_wd + 404 + k), a1);
          a2 = dot2f(hp, *(const h2*)(s_wd + 808 + k), a2);
          a3 = dot2f(hp, *(const h2*)(s_wd + 1212 + k), a3);
        }
      };
      dproc(r0, ks); dproc(r1, ks + 16); dproc(r2, ks + 32);
      if (ks < 2) dproc(r3, 48 + ks);
      a0 += __shfl_xor(a0, 1); a0 += __shfl_xor(a0, 2); a0 += __shfl_xor(a0, 4); a0 += __shfl_xor(a0, 8);
      a1 += __shfl_xor(a1, 1); a1 += __shfl_xor(a1, 2); a1 += __shfl_xor(a1, 4); a1 += __shfl_xor(a1, 8);
      a2 += __shfl_xor(a2, 1); a2 += __shfl_xor(a2, 2); a2 += __shfl_xor(a2, 4); a2 += __shfl_xor(a2, 8);
      a3 += __shfl_xor(a3, 1); a3 += __shfl_xor(a3, 2); a3 += __shfl_xor(a3, 4); a3 += __shfl_xor(a3, 8);
      float o = a0;
      if (ks == 1) o = a1;
      if (ks == 2) o = a2;
      if (ks == 3) o = a3;
      if (ks < 4) out[(rg * T_ + s) * 4 + ks] = o + bdv;
    }
  }
}

__global__ __launch_bounds__(NTHR, 1) void rnn_kernel(
    const float* __restrict__ xr, const float* __restrict__ xc,
    const float* __restrict__ Wx0, const float* __restrict__ Wh0, const float* __restrict__ b0,
    const float* __restrict__ Wx1, const float* __restrict__ Wh1, const float* __restrict__ b1,
    const float* __restrict__ Wd, const float* __restrict__ bd,
    float* __restrict__ out, float* ws)
{
  __shared__ __align__(16) unsigned char smem[SMEMB];
  const int bid = blockIdx.x;
  const int grp = bid >> 5, j = bid & 31;
  int* flags = (int*)ws;                       // [3][NG][1024]
  int* f0 = flags + grp * 1024;
  int* f1 = flags + NG * 1024 + grp * 1024;
  int* fD = flags + 2 * NG * 1024 + grp * 1024;
  _Float16* h0buf = (_Float16*)((char*)ws + 98304);    // [NG][4][SLOT]
  _Float16* h1buf = h0buf + NG * 4 * SLOT;
  _Float16* h0g = h0buf + grp * 4 * SLOT;
  _Float16* h1g = h1buf + grp * 4 * SLOT;
  if (j < N0)            run_l0(j, grp, xr, xc, Wx0, Wh0, b0, h0g, f0, f1, smem);
  else if (j < N0 + N1)  run_l1(j - N0, grp, Wx1, Wh1, b1, h0g, h1g, f0, f1, fD, smem);
  else                   run_dense(grp, Wd, bd, h1g, out, f1, fD, smem);
}

extern "C" void kernel_launch(void* const* d_in, const int* in_sizes, int n_in,
                              void* d_out, int out_size, void* d_ws, size_t ws_size,
                              hipStream_t stream) {
  const float* xr  = (const float*)d_in[0];
  const float* xc  = (const float*)d_in[1];
  const float* Wx0 = (const float*)d_in[2];
  const float* Wh0 = (const float*)d_in[3];
  const float* b0  = (const float*)d_in[4];
  const float* Wx1 = (const float*)d_in[5];
  const float* Wh1 = (const float*)d_in[6];
  const float* b1  = (const float*)d_in[7];
  const float* Wd  = (const float*)d_in[8];
  const float* bd  = (const float*)d_in[9];
  float* out = (float*)d_out;
  float* ws  = (float*)d_ws;

  // zero flags (3*8*1024 ints = 98304B) + both h rings
  hipMemsetAsync(d_ws, 0, 98304 + 2 * 819200, stream);
  hipLaunchKernelGGL(rnn_kernel, dim3(NBLK), dim3(NTHR), 0, stream,
                     xr, xc, Wx0, Wh0, b0, Wx1, Wh1, b1, Wd, bd, out, ws);
}